// Round 15
// baseline (289.626 us; speedup 1.0000x reference)
//
#include <hip/hip_runtime.h>

typedef __attribute__((ext_vector_type(8))) short short8;
typedef __attribute__((ext_vector_type(4))) float f32x4;
typedef unsigned short u16;

#define MFMA_BF16 __builtin_amdgcn_mfma_f32_16x16x32_bf16
#define S_BARRIER()  asm volatile("s_barrier" ::: "memory")
#define WAIT_LGKM0() asm volatile("s_waitcnt lgkmcnt(0)" ::: "memory")
#define WAIT_VM(n)   asm volatile("s_waitcnt vmcnt(" #n ")" ::: "memory")

__device__ __forceinline__ u16 f2bf(float f) {
    unsigned int u = __builtin_bit_cast(unsigned int, f);
    u = (u + 0x7FFFu + ((u >> 16) & 1u)) >> 16;
    return (u16)u;
}

__device__ __forceinline__ void gl_lds16(const void* g, void* l) {
    __builtin_amdgcn_global_load_lds(
        (const __attribute__((address_space(1))) unsigned int*)g,
        (__attribute__((address_space(3))) unsigned int*)l, 16, 0, 0);
}

constexpr int D = 768;
constexpr int S = 4096;
constexpr float SCALE = 0.03608439182435161f;   // 1/sqrt(768)

// decode lower-tri tile index t -> (i,j), j<=i
__device__ __forceinline__ void tri_decode(int t, int& i, int& j) {
    i = (int)((sqrtf(8.0f * t + 1.0f) - 1.0f) * 0.5f);
    while ((i + 1) * (i + 2) / 2 <= t) ++i;
    while (i * (i + 1) / 2 > t) --i;
    j = t - i * (i + 1) / 2;
}

// stage a tile (row-major global, stride 768) into linear LDS; source pre-swizzled
// so swizzled reads see logical layout (XOR involution). NT = threads in block.
template<int NCH, int NT>
__device__ __forceinline__ void stageT(const u16* __restrict__ g, u16* lds, int kcol, int tid) {
    #pragma unroll
    for (int i = 0; i < NCH; ++i) {
        const int ch = i * NT + tid;
        const int row = ch >> 3, c = ch & 7;
        const int cs = c ^ (row & 7);
        gl_lds16(g + (size_t)row * 768 + kcol + cs * 8, lds + ch * 8);
    }
}
// swizzled b128 fragment read: row's k-slice ks (32 elems -> 16B chunk)
__device__ __forceinline__ short8 ldsfrag(const u16* p, int row, int ks, int lane) {
    const int cs = (ks * 4 + (lane >> 4)) ^ (row & 7);
    return *reinterpret_cast<const short8*>(p + row * 64 + cs * 8);
}

// ---------------- convert x fp32 -> bf16 row-major ----------------
__global__ __launch_bounds__(256)
void conv_x(const float* __restrict__ x, u16* __restrict__ xb) {
    const size_t i = ((size_t)blockIdx.x * 256 + threadIdx.x) * 4;
    const float4 v = *reinterpret_cast<const float4*>(x + i);
    ushort4 o;
    o.x = f2bf(v.x); o.y = f2bf(v.y); o.z = f2bf(v.z); o.w = f2bf(v.w);
    *reinterpret_cast<ushort4*>(xb + i) = o;
}

// ------------- convert W fp32 [k][n] -> bf16 transposed [n][k] (fused [2304][768]) -------------
__global__ __launch_bounds__(256)
void conv_wt(const float* __restrict__ Wq, const float* __restrict__ Wk,
             const float* __restrict__ Wv, u16* __restrict__ WT) {
    __shared__ float t[64][65];
    const int tid = threadIdx.x;
    const int k0 = blockIdx.x * 64, n0 = blockIdx.y * 64, z = blockIdx.z;
    const float* __restrict__ W = (z == 0) ? Wq : ((z == 1) ? Wk : Wv);
    #pragma unroll
    for (int i = 0; i < 4; ++i) {
        const int e = (i * 256 + tid) * 4;
        const int r = e >> 6, c = e & 63;
        const float4 v = *reinterpret_cast<const float4*>(W + (size_t)(k0 + r) * D + n0 + c);
        t[r][c] = v.x; t[r][c + 1] = v.y; t[r][c + 2] = v.z; t[r][c + 3] = v.w;
    }
    __syncthreads();
    u16* O = WT + (size_t)z * D * D;
    #pragma unroll
    for (int i = 0; i < 4; ++i) {
        const int e = (i * 256 + tid) * 4;
        const int n = e >> 6, kq = e & 63;
        ushort4 o;
        o.x = f2bf(t[kq + 0][n]); o.y = f2bf(t[kq + 1][n]);
        o.z = f2bf(t[kq + 2][n]); o.w = f2bf(t[kq + 3][n]);
        *reinterpret_cast<ushort4*>(O + (size_t)(n0 + n) * D + k0 + kq) = o;
    }
}

// ------- QKV GEMM: 128x192 tile, 4 waves of 64x96, BK=64 dbuf, counted vmcnt -------
__global__ __launch_bounds__(256, 2)
void qkv_gemm(const u16* __restrict__ xb, const u16* __restrict__ WT,
              u16* __restrict__ qo, u16* __restrict__ ko, u16* __restrict__ vt)
{
    __shared__ u16 smem[40960];         // 80 KB: A dbuf [0,16384), B dbuf [16384,40960)
    u16* sAb = smem;
    u16* sBb = smem + 16384;
    const int tid = threadIdx.x, lane = tid & 63, w = tid >> 6;
    const int wr = w >> 1, wn = w & 1;          // wave tile 64 x 96
    const int bm = blockIdx.x * 128;
    const u16* __restrict__ A = xb + (size_t)bm * 768;
    const u16* __restrict__ B = WT + (size_t)blockIdx.y * 192 * 768;

    f32x4 acc[4][6] = {};

    stageT<4,256>(A, sAb, 0, tid);          stageT<6,256>(B, sBb, 0, tid);
    stageT<4,256>(A, sAb + 8192, 64, tid);  stageT<6,256>(B, sBb + 12288, 64, tid);
    WAIT_VM(10); S_BARRIER();

    #pragma unroll 2
    for (int kt = 0; kt < 12; ++kt) {
        const int cur = kt & 1;
        const u16* pA = sAb + cur * 8192;
        const u16* pB = sBb + cur * 12288;
        short8 a0[4], b0[6], a1[4], b1[6];
        #pragma unroll
        for (int fr = 0; fr < 4; ++fr) a0[fr] = ldsfrag(pA, wr * 64 + fr * 16 + (lane & 15), 0, lane);
        #pragma unroll
        for (int fc = 0; fc < 6; ++fc) b0[fc] = ldsfrag(pB, wn * 96 + fc * 16 + (lane & 15), 0, lane);
        #pragma unroll
        for (int fr = 0; fr < 4; ++fr)
            #pragma unroll
            for (int fc = 0; fc < 6; ++fc)
                acc[fr][fc] = MFMA_BF16(a0[fr], b0[fc], acc[fr][fc], 0, 0, 0);
        #pragma unroll
        for (int fr = 0; fr < 4; ++fr) a1[fr] = ldsfrag(pA, wr * 64 + fr * 16 + (lane & 15), 1, lane);
        #pragma unroll
        for (int fc = 0; fc < 6; ++fc) b1[fc] = ldsfrag(pB, wn * 96 + fc * 16 + (lane & 15), 1, lane);
        WAIT_LGKM0(); S_BARRIER();
        if (kt < 10) { stageT<4,256>(A, sAb + cur * 8192, (kt + 2) * 64, tid);
                       stageT<6,256>(B, sBb + cur * 12288, (kt + 2) * 64, tid); }
        __builtin_amdgcn_s_setprio(1);
        #pragma unroll
        for (int fr = 0; fr < 4; ++fr)
            #pragma unroll
            for (int fc = 0; fc < 6; ++fc)
                acc[fr][fc] = MFMA_BF16(a1[fr], b1[fc], acc[fr][fc], 0, 0, 0);
        __builtin_amdgcn_s_setprio(0);
        if (kt < 10) { WAIT_VM(10); } else { WAIT_VM(0); }
        S_BARRIER();
    }

    const int z = blockIdx.y >> 2, nb = (blockIdx.y & 3) * 192;
    if (z == 2) {
        // V: transpose via LDS (chunk-XOR swizzled), store vt[b][d][s] coalesced
        u16* sT = smem;                  // [192][128] u16, 48 KB (staging dead)
        #pragma unroll
        for (int fr = 0; fr < 4; ++fr)
            #pragma unroll
            for (int fc = 0; fc < 6; ++fc) {
                const int n  = wn * 96 + fc * 16 + (lane & 15);
                const int mb = wr * 64 + fr * 16 + (lane >> 4) * 4;
                ushort4 pk;
                pk.x = f2bf(acc[fr][fc][0]); pk.y = f2bf(acc[fr][fc][1]);
                pk.z = f2bf(acc[fr][fc][2]); pk.w = f2bf(acc[fr][fc][3]);
                *reinterpret_cast<ushort4*>(&sT[n * 128 + (mb ^ ((n & 7) << 3))]) = pk;
            }
        __syncthreads();
        const int batch = bm >> 12, s_in = bm & 4095;
        u16* __restrict__ vdst = vt + ((size_t)batch * 768 + nb) * 4096 + s_in;
        #pragma unroll
        for (int v = 0; v < 12; ++v) {
            const int ch = v * 256 + tid;
            const int dd = ch >> 4, sc = ch & 15;
            const short8 o = *reinterpret_cast<const short8*>(
                &sT[dd * 128 + ((sc * 8) ^ ((dd & 7) << 3))]);
            *reinterpret_cast<short8*>(vdst + (size_t)dd * 4096 + sc * 8) = o;
        }
    } else {
        u16* __restrict__ dst = (z == 0) ? qo : ko;
        #pragma unroll
        for (int fr = 0; fr < 4; ++fr)
            #pragma unroll
            for (int fc = 0; fc < 6; ++fc)
                #pragma unroll
                for (int r = 0; r < 4; ++r) {
                    const int m = bm + wr * 64 + fr * 16 + (lane >> 4) * 4 + r;
                    const int n = nb + wn * 96 + fc * 16 + (lane & 15);
                    dst[(size_t)m * 768 + n] = f2bf(acc[fr][fc][r]);
                }
    }
}

// ------- QK^T: 128x128 causal tiles, 4 waves of 64x64, counted vmcnt, XCD swizzle -------
// P = exp(scale*s - 10) bf16 packed tiles (coalesced via LDS), Lp 64-col partials.
__global__ __launch_bounds__(256, 2)
void qkt_gemm(const u16* __restrict__ Qg, const u16* __restrict__ Kg,
              u16* __restrict__ Pp, float* __restrict__ Lp)
{
    __shared__ u16 smem[32768];         // 64 KB: A dbuf [0,16384), B dbuf [16384,32768)
    const int tid = threadIdx.x, lane = tid & 63, w = tid >> 6;
    const int wr = w >> 1, wn = w & 1;  // wave tile 64 x 64
    const int bx = blockIdx.x;
    const int bxs = (bx & 7) * 66 + (bx >> 3);   // XCD-aware bijective remap (528 = 8*66)
    int ti, tj;
    tri_decode(bxs, ti, tj);            // 32x32 lower-tri, 528 tiles
    const int b = blockIdx.y;
    const u16* __restrict__ A = Qg + ((size_t)b * S + ti * 128) * 768;
    const u16* __restrict__ B = Kg + ((size_t)b * S + tj * 128) * 768;

    f32x4 acc[4][4] = {};

    stageT<4,256>(A, smem, 0, tid);           stageT<4,256>(B, smem + 16384, 0, tid);
    stageT<4,256>(A, smem + 8192, 64, tid);   stageT<4,256>(B, smem + 24576, 64, tid);
    WAIT_VM(8); S_BARRIER();

    #pragma unroll 2
    for (int kt = 0; kt < 12; ++kt) {
        const int cur = kt & 1;
        const u16* pA = smem + cur * 8192;
        const u16* pB = smem + 16384 + cur * 8192;
        short8 a0[4], b0[4], a1[4], b1[4];
        #pragma unroll
        for (int fr = 0; fr < 4; ++fr) a0[fr] = ldsfrag(pA, wr * 64 + fr * 16 + (lane & 15), 0, lane);
        #pragma unroll
        for (int fc = 0; fc < 4; ++fc) b0[fc] = ldsfrag(pB, wn * 64 + fc * 16 + (lane & 15), 0, lane);
        #pragma unroll
        for (int fr = 0; fr < 4; ++fr)
            #pragma unroll
            for (int fc = 0; fc < 4; ++fc)
                acc[fr][fc] = MFMA_BF16(a0[fr], b0[fc], acc[fr][fc], 0, 0, 0);
        #pragma unroll
        for (int fr = 0; fr < 4; ++fr) a1[fr] = ldsfrag(pA, wr * 64 + fr * 16 + (lane & 15), 1, lane);
        #pragma unroll
        for (int fc = 0; fc < 4; ++fc) b1[fc] = ldsfrag(pB, wn * 64 + fc * 16 + (lane & 15), 1, lane);
        WAIT_LGKM0(); S_BARRIER();
        if (kt < 10) { stageT<4,256>(A, smem + cur * 8192, (kt + 2) * 64, tid);
                       stageT<4,256>(B, smem + 16384 + cur * 8192, (kt + 2) * 64, tid); }
        __builtin_amdgcn_s_setprio(1);
        #pragma unroll
        for (int fr = 0; fr < 4; ++fr)
            #pragma unroll
            for (int fc = 0; fc < 4; ++fc)
                acc[fr][fc] = MFMA_BF16(a1[fr], b1[fc], acc[fr][fc], 0, 0, 0);
        __builtin_amdgcn_s_setprio(0);
        if (kt < 10) { WAIT_VM(8); } else { WAIT_VM(0); }
        S_BARRIER();
    }

    // epilogue: exp + causal mask -> LDS (padded 132), Lp partials, coalesced stores
    u16* sC = smem;                      // 128*132 u16 = 33 KB, staging is dead
    const bool diag = (ti == tj);
    #pragma unroll
    for (int fr = 0; fr < 4; ++fr)
        #pragma unroll
        for (int r = 0; r < 4; ++r) {
            const int ml = wr * 64 + fr * 16 + (lane >> 4) * 4 + r;
            const int gm = ti * 128 + ml;
            float rs = 0.0f;
            #pragma unroll
            for (int fc = 0; fc < 4; ++fc) {
                const int nl = wn * 64 + fc * 16 + (lane & 15);
                float p = __expf(acc[fr][fc][r] * SCALE - 10.0f);
                if (diag && (tj * 128 + nl) > gm) p = 0.0f;
                rs += p;
                sC[ml * 132 + nl] = f2bf(p);
            }
            rs += __shfl_xor(rs, 1);
            rs += __shfl_xor(rs, 2);
            rs += __shfl_xor(rs, 4);
            rs += __shfl_xor(rs, 8);
            if ((lane & 15) == 0)
                Lp[((size_t)b * 64 + tj * 2 + wn) * 4096 + gm] = rs;
        }
    __syncthreads();
    u16* __restrict__ tbase = Pp + ((size_t)b * 528 + (size_t)ti * (ti + 1) / 2 + tj) * 16384;
    #pragma unroll
    for (int v = 0; v < 8; ++v) {
        const int ch = v * 256 + tid;
        const int row = ch >> 4, c = ch & 15;
        const short8 o = *reinterpret_cast<const short8*>(&sC[row * 132 + c * 8]);
        *reinterpret_cast<short8*>(tbase + row * 128 + c * 8) = o;
    }
}

// ------------- reduce_l: combine 64-col-granular partials -> Li = 1/rowsum -------------
__global__ __launch_bounds__(256)
void reduce_l(const float* __restrict__ Lp, float* __restrict__ Li)
{
    const int row = blockIdx.x * 256 + threadIdx.x;   // 0..16383
    const int b = row >> 12, r = row & 4095;
    const int jm = 2 * (r >> 7) + 1;
    float l = 0.0f;
    for (int j = 0; j <= jm; ++j)
        l += Lp[((size_t)b * 64 + j) * 4096 + r];
    Li[row] = 1.0f / l;
}

// ---------------- PV: pure GEMM, O = (P @ V^T) * Li ----------------
// 4 waves of 128x48, 256 thr, 80 KB -> 2 WG/CU.
// Mapping = complementary pairing AND XCD-sibling grouping:
//   bid = 8t + x (x = XCD under round-robin), t in [0,32) per half, u = t>>2, dq = t&3.
//   half 0 (bid<256): G = 64 + 8x + u  (i in [16,32))
//   half 1           : G = 63 - (8x+u) (i in [0,16))
//   -> 4 dq siblings of each (i,b) group share one XCD (P panel L2-resident once),
//   -> CU c's two WGs (bids c, c+256) have i1+i2 ~ 31 (constant work per CU).
__global__ __launch_bounds__(256)
void pv_gemm(const u16* __restrict__ Pp, const u16* __restrict__ Vt,
             const float* __restrict__ Li, float* __restrict__ out)
{
    __shared__ u16 sV[2][192 * 64];      // 48 KB
    __shared__ u16 sP[2][128 * 64];      // 32 KB  (total 80 KB -> 2 WG/CU)
    const int tid  = threadIdx.x;
    const int lane = tid & 63;
    const int wd   = tid >> 6;           // 0..3 (48 d-cols each); all waves span 128 q-rows
    const int bid  = blockIdx.x;
    const int x    = bid & 7;            // XCD (round-robin dispatch)
    const int t    = (bid & 255) >> 3;   // 0..31
    const int u    = t >> 2;             // 0..7
    const int dq   = t & 3;
    const int s    = x * 8 + u;          // 0..63
    const int G    = (bid < 256) ? (64 + s) : (63 - s);   // group 0..127
    const int i    = G >> 2;             // 0..31, cost ~ i+1
    const int b    = G & 3;
    const int q0   = i * 128, d0 = dq * 192;
    const int nkt  = 2 * i + 2;
    const u16* __restrict__ Pt  = Pp + ((size_t)b * 528 + (size_t)i * (i + 1) / 2) * 16384;
    const u16* __restrict__ vtb = Vt + ((size_t)b * D + d0) * S;

    f32x4 acc[8][3] = {};

    auto stage_v = [&](int buf, int kt) {
        #pragma unroll
        for (int n = 0; n < 6; ++n) {
            const int ch  = n * 256 + tid;
            const int row = ch >> 3;
            const int csw = (ch & 7) ^ (row & 7);
            gl_lds16(vtb + (size_t)row * S + kt * 64 + csw * 8, &sV[buf][ch * 8]);
        }
    };
    auto stage_p = [&](int buf, int kt) {
        const u16* base = Pt + (size_t)(kt >> 1) * 16384 + (kt & 1) * 64;
        #pragma unroll
        for (int n = 0; n < 4; ++n) {
            const int ch  = n * 256 + tid;
            const int row = ch >> 3;
            const int csw = (ch & 7) ^ (row & 7);
            gl_lds16(base + row * 128 + csw * 8, &sP[buf][ch * 8]);
        }
    };

    stage_v(0, 0); stage_p(0, 0);
    __syncthreads();
    int cur = 0;
    for (int kt = 0; kt < nkt; ++kt) {
        if (kt + 1 < nkt) { stage_v(cur ^ 1, kt + 1); stage_p(cur ^ 1, kt + 1); }
        #pragma unroll
        for (int ks = 0; ks < 2; ++ks) {
            short8 a[8];
            #pragma unroll
            for (int fr = 0; fr < 8; ++fr) {
                const int row = fr * 16 + (lane & 15);
                const int cch = (ks * 4 + (lane >> 4)) ^ (row & 7);
                a[fr] = *reinterpret_cast<const short8*>(&sP[cur][row * 64 + cch * 8]);
            }
            #pragma unroll
            for (int fc = 0; fc < 3; ++fc) {
                const int dr  = wd * 48 + fc * 16 + (lane & 15);
                const int vch = (ks * 4 + (lane >> 4)) ^ (dr & 7);
                const short8 bv = *reinterpret_cast<const short8*>(&sV[cur][dr * 64 + vch * 8]);
                #pragma unroll
                for (int fr = 0; fr < 8; ++fr)
                    acc[fr][fc] = MFMA_BF16(a[fr], bv, acc[fr][fc], 0, 0, 0);
            }
        }
        __syncthreads();
        cur ^= 1;
    }

    #pragma unroll
    for (int fr = 0; fr < 8; ++fr)
        #pragma unroll
        for (int rr = 0; rr < 4; ++rr) {
            const int row = q0 + fr * 16 + (lane >> 4) * 4 + rr;
            const float linv = Li[b * 4096 + row];
            #pragma unroll
            for (int fc = 0; fc < 3; ++fc) {
                const int col = d0 + wd * 48 + fc * 16 + (lane & 15);
                out[((size_t)b * S + row) * D + col] = acc[fr][fc][rr] * linv;
            }
        }
}

extern "C" void kernel_launch(void* const* d_in, const int* in_sizes, int n_in,
                              void* d_out, int out_size, void* d_ws, size_t ws_size,
                              hipStream_t stream) {
    const float* x  = (const float*)d_in[0];
    const float* Wq = (const float*)d_in[1];
    const float* Wk = (const float*)d_in[2];
    const float* Wv = (const float*)d_in[3];
    float* out = (float*)d_out;

    const size_t SD = (size_t)16384 * 768;
    u16* q  = (u16*)d_ws;
    u16* k  = q  + SD;
    u16* vt = k  + SD;
    u16* xb = vt + SD;
    u16* WT = xb + SD;                         // [2304][768] bf16
    u16* Pp = WT + (size_t)3 * 768 * 768;      // 4*528*16384 bf16 packed P tiles
    float* Lp = (float*)(Pp + (size_t)4 * 528 * 16384);   // 4*64*4096 f32
    float* Li = Lp + (size_t)4 * 64 * 4096;
    (void)in_sizes; (void)n_in; (void)out_size; (void)ws_size;

    conv_x  <<<12288, 256, 0, stream>>>(x, xb);
    conv_wt <<<dim3(12, 12, 3), 256, 0, stream>>>(Wq, Wk, Wv, WT);
    qkv_gemm<<<dim3(128, 12), 256, 0, stream>>>(xb, WT, q, k, vt);
    qkt_gemm<<<dim3(528, 4), 256, 0, stream>>>(q, k, Pp, Lp);
    reduce_l<<<64, 256, 0, stream>>>(Lp, Li);
    pv_gemm <<<512, 256, 0, stream>>>(Pp, vt, Li, out);
}

// Round 16
// 253.098 us; speedup vs baseline: 1.1443x; 1.1443x over previous
//
#include <hip/hip_runtime.h>

typedef __attribute__((ext_vector_type(8))) short short8;
typedef __attribute__((ext_vector_type(4))) float f32x4;
typedef unsigned short u16;

#define MFMA_BF16 __builtin_amdgcn_mfma_f32_16x16x32_bf16
#define S_BARRIER()  asm volatile("s_barrier" ::: "memory")
#define WAIT_LGKM0() asm volatile("s_waitcnt lgkmcnt(0)" ::: "memory")
#define WAIT_VM(n)   asm volatile("s_waitcnt vmcnt(" #n ")" ::: "memory")

__device__ __forceinline__ u16 f2bf(float f) {
    unsigned int u = __builtin_bit_cast(unsigned int, f);
    u = (u + 0x7FFFu + ((u >> 16) & 1u)) >> 16;
    return (u16)u;
}

__device__ __forceinline__ void gl_lds16(const void* g, void* l) {
    __builtin_amdgcn_global_load_lds(
        (const __attribute__((address_space(1))) unsigned int*)g,
        (__attribute__((address_space(3))) unsigned int*)l, 16, 0, 0);
}

constexpr int D = 768;
constexpr int S = 4096;
constexpr float SCALE = 0.03608439182435161f;   // 1/sqrt(768)

// decode lower-tri tile index t -> (i,j), j<=i
__device__ __forceinline__ void tri_decode(int t, int& i, int& j) {
    i = (int)((sqrtf(8.0f * t + 1.0f) - 1.0f) * 0.5f);
    while ((i + 1) * (i + 2) / 2 <= t) ++i;
    while (i * (i + 1) / 2 > t) --i;
    j = t - i * (i + 1) / 2;
}

// stage a tile (row-major global, stride 768) into linear LDS; source pre-swizzled
// so swizzled reads see logical layout (XOR involution). NT = threads in block.
template<int NCH, int NT>
__device__ __forceinline__ void stageT(const u16* __restrict__ g, u16* lds, int kcol, int tid) {
    #pragma unroll
    for (int i = 0; i < NCH; ++i) {
        const int ch = i * NT + tid;
        const int row = ch >> 3, c = ch & 7;
        const int cs = c ^ (row & 7);
        gl_lds16(g + (size_t)row * 768 + kcol + cs * 8, lds + ch * 8);
    }
}
// swizzled b128 fragment read: row's k-slice ks (32 elems -> 16B chunk)
__device__ __forceinline__ short8 ldsfrag(const u16* p, int row, int ks, int lane) {
    const int cs = (ks * 4 + (lane >> 4)) ^ (row & 7);
    return *reinterpret_cast<const short8*>(p + row * 64 + cs * 8);
}

// ---------------- convert x fp32 -> bf16 row-major ----------------
__global__ __launch_bounds__(256)
void conv_x(const float* __restrict__ x, u16* __restrict__ xb) {
    const size_t i = ((size_t)blockIdx.x * 256 + threadIdx.x) * 4;
    const float4 v = *reinterpret_cast<const float4*>(x + i);
    ushort4 o;
    o.x = f2bf(v.x); o.y = f2bf(v.y); o.z = f2bf(v.z); o.w = f2bf(v.w);
    *reinterpret_cast<ushort4*>(xb + i) = o;
}

// ------------- convert W fp32 [k][n] -> bf16 transposed [n][k] (fused [2304][768]) -------------
__global__ __launch_bounds__(256)
void conv_wt(const float* __restrict__ Wq, const float* __restrict__ Wk,
             const float* __restrict__ Wv, u16* __restrict__ WT) {
    __shared__ float t[64][65];
    const int tid = threadIdx.x;
    const int k0 = blockIdx.x * 64, n0 = blockIdx.y * 64, z = blockIdx.z;
    const float* __restrict__ W = (z == 0) ? Wq : ((z == 1) ? Wk : Wv);
    #pragma unroll
    for (int i = 0; i < 4; ++i) {
        const int e = (i * 256 + tid) * 4;
        const int r = e >> 6, c = e & 63;
        const float4 v = *reinterpret_cast<const float4*>(W + (size_t)(k0 + r) * D + n0 + c);
        t[r][c] = v.x; t[r][c + 1] = v.y; t[r][c + 2] = v.z; t[r][c + 3] = v.w;
    }
    __syncthreads();
    u16* O = WT + (size_t)z * D * D;
    #pragma unroll
    for (int i = 0; i < 4; ++i) {
        const int e = (i * 256 + tid) * 4;
        const int n = e >> 6, kq = e & 63;
        ushort4 o;
        o.x = f2bf(t[kq + 0][n]); o.y = f2bf(t[kq + 1][n]);
        o.z = f2bf(t[kq + 2][n]); o.w = f2bf(t[kq + 3][n]);
        *reinterpret_cast<ushort4*>(O + (size_t)(n0 + n) * D + k0 + kq) = o;
    }
}

// ------- QKV GEMM: 128x192 tile, 4 waves of 64x96, BK=64 dbuf, counted vmcnt -------
__global__ __launch_bounds__(256, 2)
void qkv_gemm(const u16* __restrict__ xb, const u16* __restrict__ WT,
              u16* __restrict__ qo, u16* __restrict__ ko, u16* __restrict__ vt)
{
    __shared__ u16 smem[40960];         // 80 KB: A dbuf [0,16384), B dbuf [16384,40960)
    u16* sAb = smem;
    u16* sBb = smem + 16384;
    const int tid = threadIdx.x, lane = tid & 63, w = tid >> 6;
    const int wr = w >> 1, wn = w & 1;          // wave tile 64 x 96
    const int bm = blockIdx.x * 128;
    const u16* __restrict__ A = xb + (size_t)bm * 768;
    const u16* __restrict__ B = WT + (size_t)blockIdx.y * 192 * 768;

    f32x4 acc[4][6] = {};

    stageT<4,256>(A, sAb, 0, tid);          stageT<6,256>(B, sBb, 0, tid);
    stageT<4,256>(A, sAb + 8192, 64, tid);  stageT<6,256>(B, sBb + 12288, 64, tid);
    WAIT_VM(10); S_BARRIER();

    #pragma unroll 2
    for (int kt = 0; kt < 12; ++kt) {
        const int cur = kt & 1;
        const u16* pA = sAb + cur * 8192;
        const u16* pB = sBb + cur * 12288;
        short8 a0[4], b0[6], a1[4], b1[6];
        #pragma unroll
        for (int fr = 0; fr < 4; ++fr) a0[fr] = ldsfrag(pA, wr * 64 + fr * 16 + (lane & 15), 0, lane);
        #pragma unroll
        for (int fc = 0; fc < 6; ++fc) b0[fc] = ldsfrag(pB, wn * 96 + fc * 16 + (lane & 15), 0, lane);
        #pragma unroll
        for (int fr = 0; fr < 4; ++fr)
            #pragma unroll
            for (int fc = 0; fc < 6; ++fc)
                acc[fr][fc] = MFMA_BF16(a0[fr], b0[fc], acc[fr][fc], 0, 0, 0);
        #pragma unroll
        for (int fr = 0; fr < 4; ++fr) a1[fr] = ldsfrag(pA, wr * 64 + fr * 16 + (lane & 15), 1, lane);
        #pragma unroll
        for (int fc = 0; fc < 6; ++fc) b1[fc] = ldsfrag(pB, wn * 96 + fc * 16 + (lane & 15), 1, lane);
        WAIT_LGKM0(); S_BARRIER();
        if (kt < 10) { stageT<4,256>(A, sAb + cur * 8192, (kt + 2) * 64, tid);
                       stageT<6,256>(B, sBb + cur * 12288, (kt + 2) * 64, tid); }
        __builtin_amdgcn_s_setprio(1);
        #pragma unroll
        for (int fr = 0; fr < 4; ++fr)
            #pragma unroll
            for (int fc = 0; fc < 6; ++fc)
                acc[fr][fc] = MFMA_BF16(a1[fr], b1[fc], acc[fr][fc], 0, 0, 0);
        __builtin_amdgcn_s_setprio(0);
        if (kt < 10) { WAIT_VM(10); } else { WAIT_VM(0); }
        S_BARRIER();
    }

    const int z = blockIdx.y >> 2, nb = (blockIdx.y & 3) * 192;
    if (z == 2) {
        // V: transpose via LDS (chunk-XOR swizzled), store vt[b][d][s] coalesced
        u16* sT = smem;                  // [192][128] u16, 48 KB (staging dead)
        #pragma unroll
        for (int fr = 0; fr < 4; ++fr)
            #pragma unroll
            for (int fc = 0; fc < 6; ++fc) {
                const int n  = wn * 96 + fc * 16 + (lane & 15);
                const int mb = wr * 64 + fr * 16 + (lane >> 4) * 4;
                ushort4 pk;
                pk.x = f2bf(acc[fr][fc][0]); pk.y = f2bf(acc[fr][fc][1]);
                pk.z = f2bf(acc[fr][fc][2]); pk.w = f2bf(acc[fr][fc][3]);
                *reinterpret_cast<ushort4*>(&sT[n * 128 + (mb ^ ((n & 7) << 3))]) = pk;
            }
        __syncthreads();
        const int batch = bm >> 12, s_in = bm & 4095;
        u16* __restrict__ vdst = vt + ((size_t)batch * 768 + nb) * 4096 + s_in;
        #pragma unroll
        for (int v = 0; v < 12; ++v) {
            const int ch = v * 256 + tid;
            const int dd = ch >> 4, sc = ch & 15;
            const short8 o = *reinterpret_cast<const short8*>(
                &sT[dd * 128 + ((sc * 8) ^ ((dd & 7) << 3))]);
            *reinterpret_cast<short8*>(vdst + (size_t)dd * 4096 + sc * 8) = o;
        }
    } else {
        u16* __restrict__ dst = (z == 0) ? qo : ko;
        #pragma unroll
        for (int fr = 0; fr < 4; ++fr)
            #pragma unroll
            for (int fc = 0; fc < 6; ++fc)
                #pragma unroll
                for (int r = 0; r < 4; ++r) {
                    const int m = bm + wr * 64 + fr * 16 + (lane >> 4) * 4 + r;
                    const int n = nb + wn * 96 + fc * 16 + (lane & 15);
                    dst[(size_t)m * 768 + n] = f2bf(acc[fr][fc][r]);
                }
    }
}

// ------- QK^T: 128x128 causal tiles, 4 waves of 64x64, counted vmcnt, XCD swizzle -------
// P = exp(scale*s - 10) bf16 packed tiles (coalesced via LDS), Lp 64-col partials.
__global__ __launch_bounds__(256, 2)
void qkt_gemm(const u16* __restrict__ Qg, const u16* __restrict__ Kg,
              u16* __restrict__ Pp, float* __restrict__ Lp)
{
    __shared__ u16 smem[32768];         // 64 KB: A dbuf [0,16384), B dbuf [16384,32768)
    const int tid = threadIdx.x, lane = tid & 63, w = tid >> 6;
    const int wr = w >> 1, wn = w & 1;  // wave tile 64 x 64
    const int bx = blockIdx.x;
    const int bxs = (bx & 7) * 66 + (bx >> 3);   // XCD-aware bijective remap (528 = 8*66)
    int ti, tj;
    tri_decode(bxs, ti, tj);            // 32x32 lower-tri, 528 tiles
    const int b = blockIdx.y;
    const u16* __restrict__ A = Qg + ((size_t)b * S + ti * 128) * 768;
    const u16* __restrict__ B = Kg + ((size_t)b * S + tj * 128) * 768;

    f32x4 acc[4][4] = {};

    stageT<4,256>(A, smem, 0, tid);           stageT<4,256>(B, smem + 16384, 0, tid);
    stageT<4,256>(A, smem + 8192, 64, tid);   stageT<4,256>(B, smem + 24576, 64, tid);
    WAIT_VM(8); S_BARRIER();

    #pragma unroll 2
    for (int kt = 0; kt < 12; ++kt) {
        const int cur = kt & 1;
        const u16* pA = smem + cur * 8192;
        const u16* pB = smem + 16384 + cur * 8192;
        short8 a0[4], b0[4], a1[4], b1[4];
        #pragma unroll
        for (int fr = 0; fr < 4; ++fr) a0[fr] = ldsfrag(pA, wr * 64 + fr * 16 + (lane & 15), 0, lane);
        #pragma unroll
        for (int fc = 0; fc < 4; ++fc) b0[fc] = ldsfrag(pB, wn * 64 + fc * 16 + (lane & 15), 0, lane);
        #pragma unroll
        for (int fr = 0; fr < 4; ++fr)
            #pragma unroll
            for (int fc = 0; fc < 4; ++fc)
                acc[fr][fc] = MFMA_BF16(a0[fr], b0[fc], acc[fr][fc], 0, 0, 0);
        #pragma unroll
        for (int fr = 0; fr < 4; ++fr) a1[fr] = ldsfrag(pA, wr * 64 + fr * 16 + (lane & 15), 1, lane);
        #pragma unroll
        for (int fc = 0; fc < 4; ++fc) b1[fc] = ldsfrag(pB, wn * 64 + fc * 16 + (lane & 15), 1, lane);
        WAIT_LGKM0(); S_BARRIER();
        if (kt < 10) { stageT<4,256>(A, smem + cur * 8192, (kt + 2) * 64, tid);
                       stageT<4,256>(B, smem + 16384 + cur * 8192, (kt + 2) * 64, tid); }
        __builtin_amdgcn_s_setprio(1);
        #pragma unroll
        for (int fr = 0; fr < 4; ++fr)
            #pragma unroll
            for (int fc = 0; fc < 4; ++fc)
                acc[fr][fc] = MFMA_BF16(a1[fr], b1[fc], acc[fr][fc], 0, 0, 0);
        __builtin_amdgcn_s_setprio(0);
        if (kt < 10) { WAIT_VM(8); } else { WAIT_VM(0); }
        S_BARRIER();
    }

    // epilogue: exp + causal mask -> LDS (padded 132), Lp partials, coalesced stores
    u16* sC = smem;                      // 128*132 u16 = 33 KB, staging is dead
    const bool diag = (ti == tj);
    #pragma unroll
    for (int fr = 0; fr < 4; ++fr)
        #pragma unroll
        for (int r = 0; r < 4; ++r) {
            const int ml = wr * 64 + fr * 16 + (lane >> 4) * 4 + r;
            const int gm = ti * 128 + ml;
            float rs = 0.0f;
            #pragma unroll
            for (int fc = 0; fc < 4; ++fc) {
                const int nl = wn * 64 + fc * 16 + (lane & 15);
                float p = __expf(acc[fr][fc][r] * SCALE - 10.0f);
                if (diag && (tj * 128 + nl) > gm) p = 0.0f;
                rs += p;
                sC[ml * 132 + nl] = f2bf(p);
            }
            rs += __shfl_xor(rs, 1);
            rs += __shfl_xor(rs, 2);
            rs += __shfl_xor(rs, 4);
            rs += __shfl_xor(rs, 8);
            if ((lane & 15) == 0)
                Lp[((size_t)b * 64 + tj * 2 + wn) * 4096 + gm] = rs;
        }
    __syncthreads();
    u16* __restrict__ tbase = Pp + ((size_t)b * 528 + (size_t)ti * (ti + 1) / 2 + tj) * 16384;
    #pragma unroll
    for (int v = 0; v < 8; ++v) {
        const int ch = v * 256 + tid;
        const int row = ch >> 4, c = ch & 15;
        const short8 o = *reinterpret_cast<const short8*>(&sC[row * 132 + c * 8]);
        *reinterpret_cast<short8*>(tbase + row * 128 + c * 8) = o;
    }
}

// ------------- reduce_l: combine 64-col-granular partials -> Li = 1/rowsum -------------
__global__ __launch_bounds__(256)
void reduce_l(const float* __restrict__ Lp, float* __restrict__ Li)
{
    const int row = blockIdx.x * 256 + threadIdx.x;   // 0..16383
    const int b = row >> 12, r = row & 4095;
    const int jm = 2 * (r >> 7) + 1;
    float l = 0.0f;
    for (int j = 0; j <= jm; ++j)
        l += Lp[((size_t)b * 64 + j) * 4096 + r];
    Li[row] = 1.0f / l;
}

// ---------------- PV: pure GEMM, O = (P @ V^T) * Li ----------------
// 4 waves of 128x48, 256 thr, 80 KB -> 2 WG/CU; complementary rank pairing.
__global__ __launch_bounds__(256)
void pv_gemm(const u16* __restrict__ Pp, const u16* __restrict__ Vt,
             const float* __restrict__ Li, float* __restrict__ out)
{
    __shared__ u16 sV[2][192 * 64];      // 48 KB
    __shared__ u16 sP[2][128 * 64];      // 32 KB  (total 80 KB -> 2 WG/CU)
    const int tid  = threadIdx.x;
    const int lane = tid & 63;
    const int wd   = tid >> 6;           // 0..3 (48 d-cols each); all waves span 128 q-rows
    const int bid  = blockIdx.x;
    const int rank = (bid < 256) ? bid : 767 - bid;
    const int i    = rank >> 4;          // 0..31, cost ~ i+1
    const int b    = (rank >> 2) & 3;
    const int dq   = rank & 3;
    const int q0   = i * 128, d0 = dq * 192;
    const int nkt  = 2 * i + 2;
    const u16* __restrict__ Pt  = Pp + ((size_t)b * 528 + (size_t)i * (i + 1) / 2) * 16384;
    const u16* __restrict__ vtb = Vt + ((size_t)b * D + d0) * S;

    f32x4 acc[8][3] = {};

    auto stage_v = [&](int buf, int kt) {
        #pragma unroll
        for (int n = 0; n < 6; ++n) {
            const int ch  = n * 256 + tid;
            const int row = ch >> 3;
            const int csw = (ch & 7) ^ (row & 7);
            gl_lds16(vtb + (size_t)row * S + kt * 64 + csw * 8, &sV[buf][ch * 8]);
        }
    };
    auto stage_p = [&](int buf, int kt) {
        const u16* base = Pt + (size_t)(kt >> 1) * 16384 + (kt & 1) * 64;
        #pragma unroll
        for (int n = 0; n < 4; ++n) {
            const int ch  = n * 256 + tid;
            const int row = ch >> 3;
            const int csw = (ch & 7) ^ (row & 7);
            gl_lds16(base + row * 128 + csw * 8, &sP[buf][ch * 8]);
        }
    };

    stage_v(0, 0); stage_p(0, 0);
    __syncthreads();
    int cur = 0;
    for (int kt = 0; kt < nkt; ++kt) {
        if (kt + 1 < nkt) { stage_v(cur ^ 1, kt + 1); stage_p(cur ^ 1, kt + 1); }
        #pragma unroll
        for (int ks = 0; ks < 2; ++ks) {
            short8 a[8];
            #pragma unroll
            for (int fr = 0; fr < 8; ++fr) {
                const int row = fr * 16 + (lane & 15);
                const int cch = (ks * 4 + (lane >> 4)) ^ (row & 7);
                a[fr] = *reinterpret_cast<const short8*>(&sP[cur][row * 64 + cch * 8]);
            }
            #pragma unroll
            for (int fc = 0; fc < 3; ++fc) {
                const int dr  = wd * 48 + fc * 16 + (lane & 15);
                const int vch = (ks * 4 + (lane >> 4)) ^ (dr & 7);
                const short8 bv = *reinterpret_cast<const short8*>(&sV[cur][dr * 64 + vch * 8]);
                #pragma unroll
                for (int fr = 0; fr < 8; ++fr)
                    acc[fr][fc] = MFMA_BF16(a[fr], bv, acc[fr][fc], 0, 0, 0);
            }
        }
        __syncthreads();
        cur ^= 1;
    }

    #pragma unroll
    for (int fr = 0; fr < 8; ++fr)
        #pragma unroll
        for (int rr = 0; rr < 4; ++rr) {
            const int row = q0 + fr * 16 + (lane >> 4) * 4 + rr;
            const float linv = Li[b * 4096 + row];
            #pragma unroll
            for (int fc = 0; fc < 3; ++fc) {
                const int col = d0 + wd * 48 + fc * 16 + (lane & 15);
                out[((size_t)b * S + row) * D + col] = acc[fr][fc][rr] * linv;
            }
        }
}

extern "C" void kernel_launch(void* const* d_in, const int* in_sizes, int n_in,
                              void* d_out, int out_size, void* d_ws, size_t ws_size,
                              hipStream_t stream) {
    const float* x  = (const float*)d_in[0];
    const float* Wq = (const float*)d_in[1];
    const float* Wk = (const float*)d_in[2];
    const float* Wv = (const float*)d_in[3];
    float* out = (float*)d_out;

    const size_t SD = (size_t)16384 * 768;
    u16* q  = (u16*)d_ws;
    u16* k  = q  + SD;
    u16* vt = k  + SD;
    u16* xb = vt + SD;
    u16* WT = xb + SD;                         // [2304][768] bf16
    u16* Pp = WT + (size_t)3 * 768 * 768;      // 4*528*16384 bf16 packed P tiles
    float* Lp = (float*)(Pp + (size_t)4 * 528 * 16384);   // 4*64*4096 f32
    float* Li = Lp + (size_t)4 * 64 * 4096;
    (void)in_sizes; (void)n_in; (void)out_size; (void)ws_size;

    conv_x  <<<12288, 256, 0, stream>>>(x, xb);
    conv_wt <<<dim3(12, 12, 3), 256, 0, stream>>>(Wq, Wk, Wv, WT);
    qkv_gemm<<<dim3(128, 12), 256, 0, stream>>>(xb, WT, q, k, vt);
    qkt_gemm<<<dim3(528, 4), 256, 0, stream>>>(q, k, Pp, Lp);
    reduce_l<<<64, 256, 0, stream>>>(Lp, Li);
    pv_gemm <<<512, 256, 0, stream>>>(Pp, vt, Li, out);
}

// Round 17
// 251.154 us; speedup vs baseline: 1.1532x; 1.0077x over previous
//
#include <hip/hip_runtime.h>

typedef __attribute__((ext_vector_type(8))) short short8;
typedef __attribute__((ext_vector_type(4))) float f32x4;
typedef unsigned short u16;

#define MFMA_BF16 __builtin_amdgcn_mfma_f32_16x16x32_bf16
#define S_BARRIER()  asm volatile("s_barrier" ::: "memory")
#define WAIT_LGKM0() asm volatile("s_waitcnt lgkmcnt(0)" ::: "memory")
#define WAIT_VM(n)   asm volatile("s_waitcnt vmcnt(" #n ")" ::: "memory")

__device__ __forceinline__ u16 f2bf(float f) {
    unsigned int u = __builtin_bit_cast(unsigned int, f);
    u = (u + 0x7FFFu + ((u >> 16) & 1u)) >> 16;
    return (u16)u;
}

__device__ __forceinline__ void gl_lds16(const void* g, void* l) {
    __builtin_amdgcn_global_load_lds(
        (const __attribute__((address_space(1))) unsigned int*)g,
        (__attribute__((address_space(3))) unsigned int*)l, 16, 0, 0);
}

constexpr int D = 768;
constexpr int S = 4096;
constexpr float SCALE = 0.03608439182435161f;   // 1/sqrt(768)

// decode lower-tri tile index t -> (i,j), j<=i
__device__ __forceinline__ void tri_decode(int t, int& i, int& j) {
    i = (int)((sqrtf(8.0f * t + 1.0f) - 1.0f) * 0.5f);
    while ((i + 1) * (i + 2) / 2 <= t) ++i;
    while (i * (i + 1) / 2 > t) --i;
    j = t - i * (i + 1) / 2;
}

// stage a tile (row-major global, stride 768) into linear LDS; source pre-swizzled
// so swizzled reads see logical layout (XOR involution). NT = threads in block.
template<int NCH, int NT>
__device__ __forceinline__ void stageT(const u16* __restrict__ g, u16* lds, int kcol, int tid) {
    #pragma unroll
    for (int i = 0; i < NCH; ++i) {
        const int ch = i * NT + tid;
        const int row = ch >> 3, c = ch & 7;
        const int cs = c ^ (row & 7);
        gl_lds16(g + (size_t)row * 768 + kcol + cs * 8, lds + ch * 8);
    }
}
// swizzled b128 fragment read: row's k-slice ks (32 elems -> 16B chunk)
__device__ __forceinline__ short8 ldsfrag(const u16* p, int row, int ks, int lane) {
    const int cs = (ks * 4 + (lane >> 4)) ^ (row & 7);
    return *reinterpret_cast<const short8*>(p + row * 64 + cs * 8);
}

// ---------------- convert x fp32 -> bf16 row-major ----------------
__global__ __launch_bounds__(256)
void conv_x(const float* __restrict__ x, u16* __restrict__ xb) {
    const size_t i = ((size_t)blockIdx.x * 256 + threadIdx.x) * 4;
    const float4 v = *reinterpret_cast<const float4*>(x + i);
    ushort4 o;
    o.x = f2bf(v.x); o.y = f2bf(v.y); o.z = f2bf(v.z); o.w = f2bf(v.w);
    *reinterpret_cast<ushort4*>(xb + i) = o;
}

// ------------- convert W fp32 [k][n] -> bf16 transposed [n][k] (fused [2304][768]) -------------
__global__ __launch_bounds__(256)
void conv_wt(const float* __restrict__ Wq, const float* __restrict__ Wk,
             const float* __restrict__ Wv, u16* __restrict__ WT) {
    __shared__ float t[64][65];
    const int tid = threadIdx.x;
    const int k0 = blockIdx.x * 64, n0 = blockIdx.y * 64, z = blockIdx.z;
    const float* __restrict__ W = (z == 0) ? Wq : ((z == 1) ? Wk : Wv);
    #pragma unroll
    for (int i = 0; i < 4; ++i) {
        const int e = (i * 256 + tid) * 4;
        const int r = e >> 6, c = e & 63;
        const float4 v = *reinterpret_cast<const float4*>(W + (size_t)(k0 + r) * D + n0 + c);
        t[r][c] = v.x; t[r][c + 1] = v.y; t[r][c + 2] = v.z; t[r][c + 3] = v.w;
    }
    __syncthreads();
    u16* O = WT + (size_t)z * D * D;
    #pragma unroll
    for (int i = 0; i < 4; ++i) {
        const int e = (i * 256 + tid) * 4;
        const int n = e >> 6, kq = e & 63;
        ushort4 o;
        o.x = f2bf(t[kq + 0][n]); o.y = f2bf(t[kq + 1][n]);
        o.z = f2bf(t[kq + 2][n]); o.w = f2bf(t[kq + 3][n]);
        *reinterpret_cast<ushort4*>(O + (size_t)(n0 + n) * D + k0 + kq) = o;
    }
}

// ------- QKV GEMM: 128x192 tile, 4 waves of 64x96, BK=64 dbuf, counted vmcnt -------
__global__ __launch_bounds__(256, 2)
void qkv_gemm(const u16* __restrict__ xb, const u16* __restrict__ WT,
              u16* __restrict__ qo, u16* __restrict__ ko, u16* __restrict__ vt)
{
    __shared__ u16 smem[40960];         // 80 KB: A dbuf [0,16384), B dbuf [16384,40960)
    u16* sAb = smem;
    u16* sBb = smem + 16384;
    const int tid = threadIdx.x, lane = tid & 63, w = tid >> 6;
    const int wr = w >> 1, wn = w & 1;          // wave tile 64 x 96
    const int bm = blockIdx.x * 128;
    const u16* __restrict__ A = xb + (size_t)bm * 768;
    const u16* __restrict__ B = WT + (size_t)blockIdx.y * 192 * 768;

    f32x4 acc[4][6] = {};

    stageT<4,256>(A, sAb, 0, tid);          stageT<6,256>(B, sBb, 0, tid);
    stageT<4,256>(A, sAb + 8192, 64, tid);  stageT<6,256>(B, sBb + 12288, 64, tid);
    WAIT_VM(10); S_BARRIER();

    #pragma unroll 2
    for (int kt = 0; kt < 12; ++kt) {
        const int cur = kt & 1;
        const u16* pA = sAb + cur * 8192;
        const u16* pB = sBb + cur * 12288;
        short8 a0[4], b0[6], a1[4], b1[6];
        #pragma unroll
        for (int fr = 0; fr < 4; ++fr) a0[fr] = ldsfrag(pA, wr * 64 + fr * 16 + (lane & 15), 0, lane);
        #pragma unroll
        for (int fc = 0; fc < 6; ++fc) b0[fc] = ldsfrag(pB, wn * 96 + fc * 16 + (lane & 15), 0, lane);
        #pragma unroll
        for (int fr = 0; fr < 4; ++fr)
            #pragma unroll
            for (int fc = 0; fc < 6; ++fc)
                acc[fr][fc] = MFMA_BF16(a0[fr], b0[fc], acc[fr][fc], 0, 0, 0);
        #pragma unroll
        for (int fr = 0; fr < 4; ++fr) a1[fr] = ldsfrag(pA, wr * 64 + fr * 16 + (lane & 15), 1, lane);
        #pragma unroll
        for (int fc = 0; fc < 6; ++fc) b1[fc] = ldsfrag(pB, wn * 96 + fc * 16 + (lane & 15), 1, lane);
        WAIT_LGKM0(); S_BARRIER();
        if (kt < 10) { stageT<4,256>(A, sAb + cur * 8192, (kt + 2) * 64, tid);
                       stageT<6,256>(B, sBb + cur * 12288, (kt + 2) * 64, tid); }
        __builtin_amdgcn_s_setprio(1);
        #pragma unroll
        for (int fr = 0; fr < 4; ++fr)
            #pragma unroll
            for (int fc = 0; fc < 6; ++fc)
                acc[fr][fc] = MFMA_BF16(a1[fr], b1[fc], acc[fr][fc], 0, 0, 0);
        __builtin_amdgcn_s_setprio(0);
        if (kt < 10) { WAIT_VM(10); } else { WAIT_VM(0); }
        S_BARRIER();
    }

    const int z = blockIdx.y >> 2, nb = (blockIdx.y & 3) * 192;
    if (z == 2) {
        // V: transpose via LDS (chunk-XOR swizzled), store vt[b][d][s] coalesced
        u16* sT = smem;                  // [192][128] u16, 48 KB (staging dead)
        #pragma unroll
        for (int fr = 0; fr < 4; ++fr)
            #pragma unroll
            for (int fc = 0; fc < 6; ++fc) {
                const int n  = wn * 96 + fc * 16 + (lane & 15);
                const int mb = wr * 64 + fr * 16 + (lane >> 4) * 4;
                ushort4 pk;
                pk.x = f2bf(acc[fr][fc][0]); pk.y = f2bf(acc[fr][fc][1]);
                pk.z = f2bf(acc[fr][fc][2]); pk.w = f2bf(acc[fr][fc][3]);
                *reinterpret_cast<ushort4*>(&sT[n * 128 + (mb ^ ((n & 7) << 3))]) = pk;
            }
        __syncthreads();
        const int batch = bm >> 12, s_in = bm & 4095;
        u16* __restrict__ vdst = vt + ((size_t)batch * 768 + nb) * 4096 + s_in;
        #pragma unroll
        for (int v = 0; v < 12; ++v) {
            const int ch = v * 256 + tid;
            const int dd = ch >> 4, sc = ch & 15;
            const short8 o = *reinterpret_cast<const short8*>(
                &sT[dd * 128 + ((sc * 8) ^ ((dd & 7) << 3))]);
            *reinterpret_cast<short8*>(vdst + (size_t)dd * 4096 + sc * 8) = o;
        }
    } else {
        u16* __restrict__ dst = (z == 0) ? qo : ko;
        #pragma unroll
        for (int fr = 0; fr < 4; ++fr)
            #pragma unroll
            for (int fc = 0; fc < 6; ++fc)
                #pragma unroll
                for (int r = 0; r < 4; ++r) {
                    const int m = bm + wr * 64 + fr * 16 + (lane >> 4) * 4 + r;
                    const int n = nb + wn * 96 + fc * 16 + (lane & 15);
                    dst[(size_t)m * 768 + n] = f2bf(acc[fr][fc][r]);
                }
    }
}

// ------- QK^T: 128x128 causal tiles, 4 waves of 64x64, counted vmcnt -------
// 1D grid 2112: XCD x = bid&7 serves batch x>>1 only (L2 working set /4);
// within an XCD, tiles walk in 4x4 tile-blocks (K/Q block set ~1.5 MB < 4 MB L2).
// P = exp(scale*s - 10) bf16 packed tiles (coalesced via LDS), Lp 64-col partials.
__global__ __launch_bounds__(256, 2)
void qkt_gemm(const u16* __restrict__ Qg, const u16* __restrict__ Kg,
              u16* __restrict__ Pp, float* __restrict__ Lp)
{
    __shared__ u16 smem[32768];         // 64 KB: A dbuf [0,16384), B dbuf [16384,32768)
    const int tid = threadIdx.x, lane = tid & 63, w = tid >> 6;
    const int wr = w >> 1, wn = w & 1;  // wave tile 64 x 64
    const int bid = blockIdx.x;          // 0..2111
    const int x   = bid & 7;             // XCD under round-robin dispatch
    const int b   = x >> 1;              // batch: 2 XCDs per batch
    const int tile_id = (bid >> 3) + 264 * (x & 1);   // 0..527 within batch
    // blocked decode: 4x4 tile-blocks over the 32x32 lower triangle.
    // block-row I holds 16*I + 10 tiles (off-diag blocks 16, diag block 10).
    int rem = tile_id, I = 0;
    while (rem >= 16 * I + 10) { rem -= 16 * I + 10; ++I; }
    int ti, tj;
    if (rem < 16 * I) {
        const int J = rem >> 4, wv = rem & 15;
        ti = 4 * I + (wv >> 2);
        tj = 4 * J + (wv & 3);
    } else {
        int li, lj;
        tri_decode(rem - 16 * I, li, lj);
        ti = 4 * I + li;
        tj = 4 * I + lj;
    }
    const u16* __restrict__ A = Qg + ((size_t)b * S + ti * 128) * 768;
    const u16* __restrict__ B = Kg + ((size_t)b * S + tj * 128) * 768;

    f32x4 acc[4][4] = {};

    stageT<4,256>(A, smem, 0, tid);           stageT<4,256>(B, smem + 16384, 0, tid);
    stageT<4,256>(A, smem + 8192, 64, tid);   stageT<4,256>(B, smem + 24576, 64, tid);
    WAIT_VM(8); S_BARRIER();

    #pragma unroll 2
    for (int kt = 0; kt < 12; ++kt) {
        const int cur = kt & 1;
        const u16* pA = smem + cur * 8192;
        const u16* pB = smem + 16384 + cur * 8192;
        short8 a0[4], b0[4], a1[4], b1[4];
        #pragma unroll
        for (int fr = 0; fr < 4; ++fr) a0[fr] = ldsfrag(pA, wr * 64 + fr * 16 + (lane & 15), 0, lane);
        #pragma unroll
        for (int fc = 0; fc < 4; ++fc) b0[fc] = ldsfrag(pB, wn * 64 + fc * 16 + (lane & 15), 0, lane);
        #pragma unroll
        for (int fr = 0; fr < 4; ++fr)
            #pragma unroll
            for (int fc = 0; fc < 4; ++fc)
                acc[fr][fc] = MFMA_BF16(a0[fr], b0[fc], acc[fr][fc], 0, 0, 0);
        #pragma unroll
        for (int fr = 0; fr < 4; ++fr) a1[fr] = ldsfrag(pA, wr * 64 + fr * 16 + (lane & 15), 1, lane);
        #pragma unroll
        for (int fc = 0; fc < 4; ++fc) b1[fc] = ldsfrag(pB, wn * 64 + fc * 16 + (lane & 15), 1, lane);
        WAIT_LGKM0(); S_BARRIER();
        if (kt < 10) { stageT<4,256>(A, smem + cur * 8192, (kt + 2) * 64, tid);
                       stageT<4,256>(B, smem + 16384 + cur * 8192, (kt + 2) * 64, tid); }
        __builtin_amdgcn_s_setprio(1);
        #pragma unroll
        for (int fr = 0; fr < 4; ++fr)
            #pragma unroll
            for (int fc = 0; fc < 4; ++fc)
                acc[fr][fc] = MFMA_BF16(a1[fr], b1[fc], acc[fr][fc], 0, 0, 0);
        __builtin_amdgcn_s_setprio(0);
        if (kt < 10) { WAIT_VM(8); } else { WAIT_VM(0); }
        S_BARRIER();
    }

    // epilogue: exp + causal mask -> LDS (padded 132), Lp partials, coalesced stores
    u16* sC = smem;                      // 128*132 u16 = 33 KB, staging is dead
    const bool diag = (ti == tj);
    #pragma unroll
    for (int fr = 0; fr < 4; ++fr)
        #pragma unroll
        for (int r = 0; r < 4; ++r) {
            const int ml = wr * 64 + fr * 16 + (lane >> 4) * 4 + r;
            const int gm = ti * 128 + ml;
            float rs = 0.0f;
            #pragma unroll
            for (int fc = 0; fc < 4; ++fc) {
                const int nl = wn * 64 + fc * 16 + (lane & 15);
                float p = __expf(acc[fr][fc][r] * SCALE - 10.0f);
                if (diag && (tj * 128 + nl) > gm) p = 0.0f;
                rs += p;
                sC[ml * 132 + nl] = f2bf(p);
            }
            rs += __shfl_xor(rs, 1);
            rs += __shfl_xor(rs, 2);
            rs += __shfl_xor(rs, 4);
            rs += __shfl_xor(rs, 8);
            if ((lane & 15) == 0)
                Lp[((size_t)b * 64 + tj * 2 + wn) * 4096 + gm] = rs;
        }
    __syncthreads();
    u16* __restrict__ tbase = Pp + ((size_t)b * 528 + (size_t)ti * (ti + 1) / 2 + tj) * 16384;
    #pragma unroll
    for (int v = 0; v < 8; ++v) {
        const int ch = v * 256 + tid;
        const int row = ch >> 4, c = ch & 15;
        const short8 o = *reinterpret_cast<const short8*>(&sC[row * 132 + c * 8]);
        *reinterpret_cast<short8*>(tbase + row * 128 + c * 8) = o;
    }
}

// ------------- reduce_l: combine 64-col-granular partials -> Li = 1/rowsum -------------
__global__ __launch_bounds__(256)
void reduce_l(const float* __restrict__ Lp, float* __restrict__ Li)
{
    const int row = blockIdx.x * 256 + threadIdx.x;   // 0..16383
    const int b = row >> 12, r = row & 4095;
    const int jm = 2 * (r >> 7) + 1;
    float l = 0.0f;
    for (int j = 0; j <= jm; ++j)
        l += Lp[((size_t)b * 64 + j) * 4096 + r];
    Li[row] = 1.0f / l;
}

// ---------------- PV: pure GEMM, O = (P @ V^T) * Li ----------------
// 4 waves of 128x48, 256 thr, 80 KB -> 2 WG/CU; complementary rank pairing.
__global__ __launch_bounds__(256)
void pv_gemm(const u16* __restrict__ Pp, const u16* __restrict__ Vt,
             const float* __restrict__ Li, float* __restrict__ out)
{
    __shared__ u16 sV[2][192 * 64];      // 48 KB
    __shared__ u16 sP[2][128 * 64];      // 32 KB  (total 80 KB -> 2 WG/CU)
    const int tid  = threadIdx.x;
    const int lane = tid & 63;
    const int wd   = tid >> 6;           // 0..3 (48 d-cols each); all waves span 128 q-rows
    const int bid  = blockIdx.x;
    const int rank = (bid < 256) ? bid : 767 - bid;
    const int i    = rank >> 4;          // 0..31, cost ~ i+1
    const int b    = (rank >> 2) & 3;
    const int dq   = rank & 3;
    const int q0   = i * 128, d0 = dq * 192;
    const int nkt  = 2 * i + 2;
    const u16* __restrict__ Pt  = Pp + ((size_t)b * 528 + (size_t)i * (i + 1) / 2) * 16384;
    const u16* __restrict__ vtb = Vt + ((size_t)b * D + d0) * S;

    f32x4 acc[8][3] = {};

    auto stage_v = [&](int buf, int kt) {
        #pragma unroll
        for (int n = 0; n < 6; ++n) {
            const int ch  = n * 256 + tid;
            const int row = ch >> 3;
            const int csw = (ch & 7) ^ (row & 7);
            gl_lds16(vtb + (size_t)row * S + kt * 64 + csw * 8, &sV[buf][ch * 8]);
        }
    };
    auto stage_p = [&](int buf, int kt) {
        const u16* base = Pt + (size_t)(kt >> 1) * 16384 + (kt & 1) * 64;
        #pragma unroll
        for (int n = 0; n < 4; ++n) {
            const int ch  = n * 256 + tid;
            const int row = ch >> 3;
            const int csw = (ch & 7) ^ (row & 7);
            gl_lds16(base + row * 128 + csw * 8, &sP[buf][ch * 8]);
        }
    };

    stage_v(0, 0); stage_p(0, 0);
    __syncthreads();
    int cur = 0;
    for (int kt = 0; kt < nkt; ++kt) {
        if (kt + 1 < nkt) { stage_v(cur ^ 1, kt + 1); stage_p(cur ^ 1, kt + 1); }
        #pragma unroll
        for (int ks = 0; ks < 2; ++ks) {
            short8 a[8];
            #pragma unroll
            for (int fr = 0; fr < 8; ++fr) {
                const int row = fr * 16 + (lane & 15);
                const int cch = (ks * 4 + (lane >> 4)) ^ (row & 7);
                a[fr] = *reinterpret_cast<const short8*>(&sP[cur][row * 64 + cch * 8]);
            }
            #pragma unroll
            for (int fc = 0; fc < 3; ++fc) {
                const int dr  = wd * 48 + fc * 16 + (lane & 15);
                const int vch = (ks * 4 + (lane >> 4)) ^ (dr & 7);
                const short8 bv = *reinterpret_cast<const short8*>(&sV[cur][dr * 64 + vch * 8]);
                #pragma unroll
                for (int fr = 0; fr < 8; ++fr)
                    acc[fr][fc] = MFMA_BF16(a[fr], bv, acc[fr][fc], 0, 0, 0);
            }
        }
        __syncthreads();
        cur ^= 1;
    }

    #pragma unroll
    for (int fr = 0; fr < 8; ++fr)
        #pragma unroll
        for (int rr = 0; rr < 4; ++rr) {
            const int row = q0 + fr * 16 + (lane >> 4) * 4 + rr;
            const float linv = Li[b * 4096 + row];
            #pragma unroll
            for (int fc = 0; fc < 3; ++fc) {
                const int col = d0 + wd * 48 + fc * 16 + (lane & 15);
                out[((size_t)b * S + row) * D + col] = acc[fr][fc][rr] * linv;
            }
        }
}

extern "C" void kernel_launch(void* const* d_in, const int* in_sizes, int n_in,
                              void* d_out, int out_size, void* d_ws, size_t ws_size,
                              hipStream_t stream) {
    const float* x  = (const float*)d_in[0];
    const float* Wq = (const float*)d_in[1];
    const float* Wk = (const float*)d_in[2];
    const float* Wv = (const float*)d_in[3];
    float* out = (float*)d_out;

    const size_t SD = (size_t)16384 * 768;
    u16* q  = (u16*)d_ws;
    u16* k  = q  + SD;
    u16* vt = k  + SD;
    u16* xb = vt + SD;
    u16* WT = xb + SD;                         // [2304][768] bf16
    u16* Pp = WT + (size_t)3 * 768 * 768;      // 4*528*16384 bf16 packed P tiles
    float* Lp = (float*)(Pp + (size_t)4 * 528 * 16384);   // 4*64*4096 f32
    float* Li = Lp + (size_t)4 * 64 * 4096;
    (void)in_sizes; (void)n_in; (void)out_size; (void)ws_size;

    conv_x  <<<12288, 256, 0, stream>>>(x, xb);
    conv_wt <<<dim3(12, 12, 3), 256, 0, stream>>>(Wq, Wk, Wv, WT);
    qkv_gemm<<<dim3(128, 12), 256, 0, stream>>>(xb, WT, q, k, vt);
    qkt_gemm<<<2112, 256, 0, stream>>>(q, k, Pp, Lp);
    reduce_l<<<64, 256, 0, stream>>>(Lp, Li);
    pv_gemm <<<512, 256, 0, stream>>>(Pp, vt, Li, out);
}

// Round 18
// 250.931 us; speedup vs baseline: 1.1542x; 1.0009x over previous
//
#include <hip/hip_runtime.h>

typedef __attribute__((ext_vector_type(8))) short short8;
typedef __attribute__((ext_vector_type(4))) float f32x4;
typedef unsigned short u16;

#define MFMA_BF16 __builtin_amdgcn_mfma_f32_16x16x32_bf16
#define S_BARRIER()  asm volatile("s_barrier" ::: "memory")
#define WAIT_LGKM0() asm volatile("s_waitcnt lgkmcnt(0)" ::: "memory")
#define WAIT_VM(n)   asm volatile("s_waitcnt vmcnt(" #n ")" ::: "memory")

__device__ __forceinline__ u16 f2bf(float f) {
    unsigned int u = __builtin_bit_cast(unsigned int, f);
    u = (u + 0x7FFFu + ((u >> 16) & 1u)) >> 16;
    return (u16)u;
}

__device__ __forceinline__ void gl_lds16(const void* g, void* l) {
    __builtin_amdgcn_global_load_lds(
        (const __attribute__((address_space(1))) unsigned int*)g,
        (__attribute__((address_space(3))) unsigned int*)l, 16, 0, 0);
}

constexpr int D = 768;
constexpr int S = 4096;
constexpr float SCALE = 0.03608439182435161f;   // 1/sqrt(768)

// decode lower-tri tile index t -> (i,j), j<=i
__device__ __forceinline__ void tri_decode(int t, int& i, int& j) {
    i = (int)((sqrtf(8.0f * t + 1.0f) - 1.0f) * 0.5f);
    while ((i + 1) * (i + 2) / 2 <= t) ++i;
    while (i * (i + 1) / 2 > t) --i;
    j = t - i * (i + 1) / 2;
}

// stage a tile (row-major global, stride 768) into linear LDS; source pre-swizzled
// so swizzled reads see logical layout (XOR involution). NT = threads in block.
template<int NCH, int NT>
__device__ __forceinline__ void stageT(const u16* __restrict__ g, u16* lds, int kcol, int tid) {
    #pragma unroll
    for (int i = 0; i < NCH; ++i) {
        const int ch = i * NT + tid;
        const int row = ch >> 3, c = ch & 7;
        const int cs = c ^ (row & 7);
        gl_lds16(g + (size_t)row * 768 + kcol + cs * 8, lds + ch * 8);
    }
}
// swizzled b128 fragment read: row's k-slice ks (32 elems -> 16B chunk)
__device__ __forceinline__ short8 ldsfrag(const u16* p, int row, int ks, int lane) {
    const int cs = (ks * 4 + (lane >> 4)) ^ (row & 7);
    return *reinterpret_cast<const short8*>(p + row * 64 + cs * 8);
}

// ---------------- convert x fp32 -> bf16 row-major ----------------
__global__ __launch_bounds__(256)
void conv_x(const float* __restrict__ x, u16* __restrict__ xb) {
    const size_t i = ((size_t)blockIdx.x * 256 + threadIdx.x) * 4;
    const float4 v = *reinterpret_cast<const float4*>(x + i);
    ushort4 o;
    o.x = f2bf(v.x); o.y = f2bf(v.y); o.z = f2bf(v.z); o.w = f2bf(v.w);
    *reinterpret_cast<ushort4*>(xb + i) = o;
}

// ------------- convert W fp32 [k][n] -> bf16 transposed [n][k] (fused [2304][768]) -------------
__global__ __launch_bounds__(256)
void conv_wt(const float* __restrict__ Wq, const float* __restrict__ Wk,
             const float* __restrict__ Wv, u16* __restrict__ WT) {
    __shared__ float t[64][65];
    const int tid = threadIdx.x;
    const int k0 = blockIdx.x * 64, n0 = blockIdx.y * 64, z = blockIdx.z;
    const float* __restrict__ W = (z == 0) ? Wq : ((z == 1) ? Wk : Wv);
    #pragma unroll
    for (int i = 0; i < 4; ++i) {
        const int e = (i * 256 + tid) * 4;
        const int r = e >> 6, c = e & 63;
        const float4 v = *reinterpret_cast<const float4*>(W + (size_t)(k0 + r) * D + n0 + c);
        t[r][c] = v.x; t[r][c + 1] = v.y; t[r][c + 2] = v.z; t[r][c + 3] = v.w;
    }
    __syncthreads();
    u16* O = WT + (size_t)z * D * D;
    #pragma unroll
    for (int i = 0; i < 4; ++i) {
        const int e = (i * 256 + tid) * 4;
        const int n = e >> 6, kq = e & 63;
        ushort4 o;
        o.x = f2bf(t[kq + 0][n]); o.y = f2bf(t[kq + 1][n]);
        o.z = f2bf(t[kq + 2][n]); o.w = f2bf(t[kq + 3][n]);
        *reinterpret_cast<ushort4*>(O + (size_t)(n0 + n) * D + k0 + kq) = o;
    }
}

// ------- QKV GEMM: 128x192 tile, 4 waves of 64x96, BK=64 dbuf, counted vmcnt -------
// 1D grid 1536: XCD x = bid&7 owns bm panels [16x,16x+16); A-panel-major walk
// (12 consecutive WGs per XCD share one 1.2 MB A panel -> L2-resident).
__global__ __launch_bounds__(256, 2)
void qkv_gemm(const u16* __restrict__ xb, const u16* __restrict__ WT,
              u16* __restrict__ qo, u16* __restrict__ ko, u16* __restrict__ vt)
{
    __shared__ u16 smem[40960];         // 80 KB: A dbuf [0,16384), B dbuf [16384,40960)
    u16* sAb = smem;
    u16* sBb = smem + 16384;
    const int tid = threadIdx.x, lane = tid & 63, w = tid >> 6;
    const int wr = w >> 1, wn = w & 1;          // wave tile 64 x 96
    const int bid = blockIdx.x;                  // 0..1535
    const int x   = bid & 7;                     // XCD under round-robin dispatch
    const int t   = bid >> 3;                    // 0..191
    const int byv = t % 12;                      // n-panel 0..11 (inner: A reuse)
    const int bm  = (x * 16 + t / 12) * 128;     // m-panel
    const u16* __restrict__ A = xb + (size_t)bm * 768;
    const u16* __restrict__ B = WT + (size_t)byv * 192 * 768;

    f32x4 acc[4][6] = {};

    stageT<4,256>(A, sAb, 0, tid);          stageT<6,256>(B, sBb, 0, tid);
    stageT<4,256>(A, sAb + 8192, 64, tid);  stageT<6,256>(B, sBb + 12288, 64, tid);
    WAIT_VM(10); S_BARRIER();

    #pragma unroll 2
    for (int kt = 0; kt < 12; ++kt) {
        const int cur = kt & 1;
        const u16* pA = sAb + cur * 8192;
        const u16* pB = sBb + cur * 12288;
        short8 a0[4], b0[6], a1[4], b1[6];
        #pragma unroll
        for (int fr = 0; fr < 4; ++fr) a0[fr] = ldsfrag(pA, wr * 64 + fr * 16 + (lane & 15), 0, lane);
        #pragma unroll
        for (int fc = 0; fc < 6; ++fc) b0[fc] = ldsfrag(pB, wn * 96 + fc * 16 + (lane & 15), 0, lane);
        #pragma unroll
        for (int fr = 0; fr < 4; ++fr)
            #pragma unroll
            for (int fc = 0; fc < 6; ++fc)
                acc[fr][fc] = MFMA_BF16(a0[fr], b0[fc], acc[fr][fc], 0, 0, 0);
        #pragma unroll
        for (int fr = 0; fr < 4; ++fr) a1[fr] = ldsfrag(pA, wr * 64 + fr * 16 + (lane & 15), 1, lane);
        #pragma unroll
        for (int fc = 0; fc < 6; ++fc) b1[fc] = ldsfrag(pB, wn * 96 + fc * 16 + (lane & 15), 1, lane);
        WAIT_LGKM0(); S_BARRIER();
        if (kt < 10) { stageT<4,256>(A, sAb + cur * 8192, (kt + 2) * 64, tid);
                       stageT<6,256>(B, sBb + cur * 12288, (kt + 2) * 64, tid); }
        __builtin_amdgcn_s_setprio(1);
        #pragma unroll
        for (int fr = 0; fr < 4; ++fr)
            #pragma unroll
            for (int fc = 0; fc < 6; ++fc)
                acc[fr][fc] = MFMA_BF16(a1[fr], b1[fc], acc[fr][fc], 0, 0, 0);
        __builtin_amdgcn_s_setprio(0);
        if (kt < 10) { WAIT_VM(10); } else { WAIT_VM(0); }
        S_BARRIER();
    }

    const int z = byv >> 2, nb = (byv & 3) * 192;
    if (z == 2) {
        // V: transpose via LDS (chunk-XOR swizzled), store vt[b][d][s] coalesced
        u16* sT = smem;                  // [192][128] u16, 48 KB (staging dead)
        #pragma unroll
        for (int fr = 0; fr < 4; ++fr)
            #pragma unroll
            for (int fc = 0; fc < 6; ++fc) {
                const int n  = wn * 96 + fc * 16 + (lane & 15);
                const int mb = wr * 64 + fr * 16 + (lane >> 4) * 4;
                ushort4 pk;
                pk.x = f2bf(acc[fr][fc][0]); pk.y = f2bf(acc[fr][fc][1]);
                pk.z = f2bf(acc[fr][fc][2]); pk.w = f2bf(acc[fr][fc][3]);
                *reinterpret_cast<ushort4*>(&sT[n * 128 + (mb ^ ((n & 7) << 3))]) = pk;
            }
        __syncthreads();
        const int batch = bm >> 12, s_in = bm & 4095;
        u16* __restrict__ vdst = vt + ((size_t)batch * 768 + nb) * 4096 + s_in;
        #pragma unroll
        for (int v = 0; v < 12; ++v) {
            const int ch = v * 256 + tid;
            const int dd = ch >> 4, sc = ch & 15;
            const short8 o = *reinterpret_cast<const short8*>(
                &sT[dd * 128 + ((sc * 8) ^ ((dd & 7) << 3))]);
            *reinterpret_cast<short8*>(vdst + (size_t)dd * 4096 + sc * 8) = o;
        }
    } else {
        u16* __restrict__ dst = (z == 0) ? qo : ko;
        #pragma unroll
        for (int fr = 0; fr < 4; ++fr)
            #pragma unroll
            for (int fc = 0; fc < 6; ++fc)
                #pragma unroll
                for (int r = 0; r < 4; ++r) {
                    const int m = bm + wr * 64 + fr * 16 + (lane >> 4) * 4 + r;
                    const int n = nb + wn * 96 + fc * 16 + (lane & 15);
                    dst[(size_t)m * 768 + n] = f2bf(acc[fr][fc][r]);
                }
    }
}

// ------- QK^T: 128x128 causal tiles, 4 waves of 64x64, counted vmcnt -------
// 1D grid 2112: XCD x = bid&7 serves batch x>>1 only (L2 working set /4);
// within an XCD, tiles walk in 4x4 tile-blocks (K/Q block set ~1.5 MB < 4 MB L2).
// P = exp(scale*s - 10) bf16 packed tiles (coalesced via LDS), Lp 64-col partials.
__global__ __launch_bounds__(256, 2)
void qkt_gemm(const u16* __restrict__ Qg, const u16* __restrict__ Kg,
              u16* __restrict__ Pp, float* __restrict__ Lp)
{
    __shared__ u16 smem[32768];         // 64 KB: A dbuf [0,16384), B dbuf [16384,32768)
    const int tid = threadIdx.x, lane = tid & 63, w = tid >> 6;
    const int wr = w >> 1, wn = w & 1;  // wave tile 64 x 64
    const int bid = blockIdx.x;          // 0..2111
    const int x   = bid & 7;             // XCD under round-robin dispatch
    const int b   = x >> 1;              // batch: 2 XCDs per batch
    const int tile_id = (bid >> 3) + 264 * (x & 1);   // 0..527 within batch
    // blocked decode: 4x4 tile-blocks over the 32x32 lower triangle.
    // block-row I holds 16*I + 10 tiles (off-diag blocks 16, diag block 10).
    int rem = tile_id, I = 0;
    while (rem >= 16 * I + 10) { rem -= 16 * I + 10; ++I; }
    int ti, tj;
    if (rem < 16 * I) {
        const int J = rem >> 4, wv = rem & 15;
        ti = 4 * I + (wv >> 2);
        tj = 4 * J + (wv & 3);
    } else {
        int li, lj;
        tri_decode(rem - 16 * I, li, lj);
        ti = 4 * I + li;
        tj = 4 * I + lj;
    }
    const u16* __restrict__ A = Qg + ((size_t)b * S + ti * 128) * 768;
    const u16* __restrict__ B = Kg + ((size_t)b * S + tj * 128) * 768;

    f32x4 acc[4][4] = {};

    stageT<4,256>(A, smem, 0, tid);           stageT<4,256>(B, smem + 16384, 0, tid);
    stageT<4,256>(A, smem + 8192, 64, tid);   stageT<4,256>(B, smem + 24576, 64, tid);
    WAIT_VM(8); S_BARRIER();

    #pragma unroll 2
    for (int kt = 0; kt < 12; ++kt) {
        const int cur = kt & 1;
        const u16* pA = smem + cur * 8192;
        const u16* pB = smem + 16384 + cur * 8192;
        short8 a0[4], b0[4], a1[4], b1[4];
        #pragma unroll
        for (int fr = 0; fr < 4; ++fr) a0[fr] = ldsfrag(pA, wr * 64 + fr * 16 + (lane & 15), 0, lane);
        #pragma unroll
        for (int fc = 0; fc < 4; ++fc) b0[fc] = ldsfrag(pB, wn * 64 + fc * 16 + (lane & 15), 0, lane);
        #pragma unroll
        for (int fr = 0; fr < 4; ++fr)
            #pragma unroll
            for (int fc = 0; fc < 4; ++fc)
                acc[fr][fc] = MFMA_BF16(a0[fr], b0[fc], acc[fr][fc], 0, 0, 0);
        #pragma unroll
        for (int fr = 0; fr < 4; ++fr) a1[fr] = ldsfrag(pA, wr * 64 + fr * 16 + (lane & 15), 1, lane);
        #pragma unroll
        for (int fc = 0; fc < 4; ++fc) b1[fc] = ldsfrag(pB, wn * 64 + fc * 16 + (lane & 15), 1, lane);
        WAIT_LGKM0(); S_BARRIER();
        if (kt < 10) { stageT<4,256>(A, smem + cur * 8192, (kt + 2) * 64, tid);
                       stageT<4,256>(B, smem + 16384 + cur * 8192, (kt + 2) * 64, tid); }
        __builtin_amdgcn_s_setprio(1);
        #pragma unroll
        for (int fr = 0; fr < 4; ++fr)
            #pragma unroll
            for (int fc = 0; fc < 4; ++fc)
                acc[fr][fc] = MFMA_BF16(a1[fr], b1[fc], acc[fr][fc], 0, 0, 0);
        __builtin_amdgcn_s_setprio(0);
        if (kt < 10) { WAIT_VM(8); } else { WAIT_VM(0); }
        S_BARRIER();
    }

    // epilogue: exp + causal mask -> LDS (padded 132), Lp partials, coalesced stores
    u16* sC = smem;                      // 128*132 u16 = 33 KB, staging is dead
    const bool diag = (ti == tj);
    #pragma unroll
    for (int fr = 0; fr < 4; ++fr)
        #pragma unroll
        for (int r = 0; r < 4; ++r) {
            const int ml = wr * 64 + fr * 16 + (lane >> 4) * 4 + r;
            const int gm = ti * 128 + ml;
            float rs = 0.0f;
            #pragma unroll
            for (int fc = 0; fc < 4; ++fc) {
                const int nl = wn * 64 + fc * 16 + (lane & 15);
                float p = __expf(acc[fr][fc][r] * SCALE - 10.0f);
                if (diag && (tj * 128 + nl) > gm) p = 0.0f;
                rs += p;
                sC[ml * 132 + nl] = f2bf(p);
            }
            rs += __shfl_xor(rs, 1);
            rs += __shfl_xor(rs, 2);
            rs += __shfl_xor(rs, 4);
            rs += __shfl_xor(rs, 8);
            if ((lane & 15) == 0)
                Lp[((size_t)b * 64 + tj * 2 + wn) * 4096 + gm] = rs;
        }
    __syncthreads();
    u16* __restrict__ tbase = Pp + ((size_t)b * 528 + (size_t)ti * (ti + 1) / 2 + tj) * 16384;
    #pragma unroll
    for (int v = 0; v < 8; ++v) {
        const int ch = v * 256 + tid;
        const int row = ch >> 4, c = ch & 15;
        const short8 o = *reinterpret_cast<const short8*>(&sC[row * 132 + c * 8]);
        *reinterpret_cast<short8*>(tbase + row * 128 + c * 8) = o;
    }
}

// ------------- reduce_l: combine 64-col-granular partials -> Li = 1/rowsum -------------
__global__ __launch_bounds__(256)
void reduce_l(const float* __restrict__ Lp, float* __restrict__ Li)
{
    const int row = blockIdx.x * 256 + threadIdx.x;   // 0..16383
    const int b = row >> 12, r = row & 4095;
    const int jm = 2 * (r >> 7) + 1;
    float l = 0.0f;
    for (int j = 0; j <= jm; ++j)
        l += Lp[((size_t)b * 64 + j) * 4096 + r];
    Li[row] = 1.0f / l;
}

// ---------------- PV: pure GEMM, O = (P @ V^T) * Li ----------------
// 4 waves of 128x48, 256 thr, 80 KB -> 2 WG/CU; complementary rank pairing.
__global__ __launch_bounds__(256)
void pv_gemm(const u16* __restrict__ Pp, const u16* __restrict__ Vt,
             const float* __restrict__ Li, float* __restrict__ out)
{
    __shared__ u16 sV[2][192 * 64];      // 48 KB
    __shared__ u16 sP[2][128 * 64];      // 32 KB  (total 80 KB -> 2 WG/CU)
    const int tid  = threadIdx.x;
    const int lane = tid & 63;
    const int wd   = tid >> 6;           // 0..3 (48 d-cols each); all waves span 128 q-rows
    const int bid  = blockIdx.x;
    const int rank = (bid < 256) ? bid : 767 - bid;
    const int i    = rank >> 4;          // 0..31, cost ~ i+1
    const int b    = (rank >> 2) & 3;
    const int dq   = rank & 3;
    const int q0   = i * 128, d0 = dq * 192;
    const int nkt  = 2 * i + 2;
    const u16* __restrict__ Pt  = Pp + ((size_t)b * 528 + (size_t)i * (i + 1) / 2) * 16384;
    const u16* __restrict__ vtb = Vt + ((size_t)b * D + d0) * S;

    f32x4 acc[8][3] = {};

    auto stage_v = [&](int buf, int kt) {
        #pragma unroll
        for (int n = 0; n < 6; ++n) {
            const int ch  = n * 256 + tid;
            const int row = ch >> 3;
            const int csw = (ch & 7) ^ (row & 7);
            gl_lds16(vtb + (size_t)row * S + kt * 64 + csw * 8, &sV[buf][ch * 8]);
        }
    };
    auto stage_p = [&](int buf, int kt) {
        const u16* base = Pt + (size_t)(kt >> 1) * 16384 + (kt & 1) * 64;
        #pragma unroll
        for (int n = 0; n < 4; ++n) {
            const int ch  = n * 256 + tid;
            const int row = ch >> 3;
            const int csw = (ch & 7) ^ (row & 7);
            gl_lds16(base + row * 128 + csw * 8, &sP[buf][ch * 8]);
        }
    };

    stage_v(0, 0); stage_p(0, 0);
    __syncthreads();
    int cur = 0;
    for (int kt = 0; kt < nkt; ++kt) {
        if (kt + 1 < nkt) { stage_v(cur ^ 1, kt + 1); stage_p(cur ^ 1, kt + 1); }
        #pragma unroll
        for (int ks = 0; ks < 2; ++ks) {
            short8 a[8];
            #pragma unroll
            for (int fr = 0; fr < 8; ++fr) {
                const int row = fr * 16 + (lane & 15);
                const int cch = (ks * 4 + (lane >> 4)) ^ (row & 7);
                a[fr] = *reinterpret_cast<const short8*>(&sP[cur][row * 64 + cch * 8]);
            }
            #pragma unroll
            for (int fc = 0; fc < 3; ++fc) {
                const int dr  = wd * 48 + fc * 16 + (lane & 15);
                const int vch = (ks * 4 + (lane >> 4)) ^ (dr & 7);
                const short8 bv = *reinterpret_cast<const short8*>(&sV[cur][dr * 64 + vch * 8]);
                #pragma unroll
                for (int fr = 0; fr < 8; ++fr)
                    acc[fr][fc] = MFMA_BF16(a[fr], bv, acc[fr][fc], 0, 0, 0);
            }
        }
        __syncthreads();
        cur ^= 1;
    }

    #pragma unroll
    for (int fr = 0; fr < 8; ++fr)
        #pragma unroll
        for (int rr = 0; rr < 4; ++rr) {
            const int row = q0 + fr * 16 + (lane >> 4) * 4 + rr;
            const float linv = Li[b * 4096 + row];
            #pragma unroll
            for (int fc = 0; fc < 3; ++fc) {
                const int col = d0 + wd * 48 + fc * 16 + (lane & 15);
                out[((size_t)b * S + row) * D + col] = acc[fr][fc][rr] * linv;
            }
        }
}

extern "C" void kernel_launch(void* const* d_in, const int* in_sizes, int n_in,
                              void* d_out, int out_size, void* d_ws, size_t ws_size,
                              hipStream_t stream) {
    const float* x  = (const float*)d_in[0];
    const float* Wq = (const float*)d_in[1];
    const float* Wk = (const float*)d_in[2];
    const float* Wv = (const float*)d_in[3];
    float* out = (float*)d_out;

    const size_t SD = (size_t)16384 * 768;
    u16* q  = (u16*)d_ws;
    u16* k  = q  + SD;
    u16* vt = k  + SD;
    u16* xb = vt + SD;
    u16* WT = xb + SD;                         // [2304][768] bf16
    u16* Pp = WT + (size_t)3 * 768 * 768;      // 4*528*16384 bf16 packed P tiles
    float* Lp = (float*)(Pp + (size_t)4 * 528 * 16384);   // 4*64*4096 f32
    float* Li = Lp + (size_t)4 * 64 * 4096;
    (void)in_sizes; (void)n_in; (void)out_size; (void)ws_size;

    conv_x  <<<12288, 256, 0, stream>>>(x, xb);
    conv_wt <<<dim3(12, 12, 3), 256, 0, stream>>>(Wq, Wk, Wv, WT);
    qkv_gemm<<<1536, 256, 0, stream>>>(xb, WT, q, k, vt);
    qkt_gemm<<<2112, 256, 0, stream>>>(q, k, Pp, Lp);
    reduce_l<<<64, 256, 0, stream>>>(Lp, Li);
    pv_gemm <<<512, 256, 0, stream>>>(Pp, vt, Li, out);
}